// Round 21
// baseline (309.399 us; speedup 1.0000x reference)
//
#include <hip/hip_runtime.h>
#include <hip/hip_bf16.h>

#define BB 32
#define SS 2048
#define DD 1024
#define UU 1024
#define MBLK 64

typedef short bf16x8 __attribute__((ext_vector_type(8)));
typedef float f32x4 __attribute__((ext_vector_type(4)));
typedef int i32x4 __attribute__((ext_vector_type(4)));
typedef unsigned int u32;

__device__ __forceinline__ unsigned short f2bf(float x) {
    union { float f; unsigned int u; } v; v.f = x;
    unsigned int r = v.u + 0x7fffu + ((v.u >> 16) & 1u);
    return (unsigned short)(r >> 16);
}

__device__ __forceinline__ f32x4 ntload4(const float* p) {
    return __builtin_nontemporal_load(reinterpret_cast<const f32x4*>(p));
}

__device__ __forceinline__ u32 cvtpk(float lo, float hi) {
    u32 r;
    asm("v_cvt_pk_bf16_f32 %0, %1, %2" : "=v"(r) : "v"(lo), "v"(hi));
    return r;
}

// ---------------- K0: zero qp2 (qproj accumulates atomically) ----------------
__global__ void zero_kernel(float* __restrict__ qp2) {
    qp2[blockIdx.x * 256 + threadIdx.x] = 0.f;
}

// ---------------- K1a: q_proj partials = query@w1 (+b1+b2 on ds==0) ----------
__global__ void qproj_kernel(const float* __restrict__ query, const float* __restrict__ w1,
                             const float* __restrict__ b1, const float* __restrict__ b2,
                             float* __restrict__ qp2) {
    __shared__ float qs[4][128];
    const int uc = blockIdx.x;   // 4
    const int bg = blockIdx.y;   // 8
    const int ds = blockIdx.z;   // 8
    const int t = threadIdx.x;   // 256
    if (t < 128) {
#pragma unroll
        for (int bi = 0; bi < 4; ++bi)
            qs[bi][t] = query[(bg * 4 + bi) * DD + ds * 128 + t];
    }
    __syncthreads();
    const int u = uc * 256 + t;
    float a0 = 0.f, a1 = 0.f, a2 = 0.f, a3 = 0.f;
    const float* wp = w1 + (size_t)(ds * 128) * UU + u;
#pragma unroll 4
    for (int d = 0; d < 128; ++d) {
        const float w = wp[(size_t)d * UU];
        a0 = fmaf(qs[0][d], w, a0);
        a1 = fmaf(qs[1][d], w, a1);
        a2 = fmaf(qs[2][d], w, a2);
        a3 = fmaf(qs[3][d], w, a3);
    }
    const float bb = (ds == 0) ? (b1[u] + b2[u]) : 0.f;
    atomicAdd(&qp2[(bg * 4 + 0) * UU + u], a0 + bb);
    atomicAdd(&qp2[(bg * 4 + 1) * UU + u], a1 + bb);
    atomicAdd(&qp2[(bg * 4 + 2) * UU + u], a2 + bb);
    atomicAdd(&qp2[(bg * 4 + 3) * UU + u], a3 + bb);
}

// ---------------- K1b: fragment-packed B for 16x16x32 (coalesced via LDS) -----
__global__ void w2q_kernel(const float* __restrict__ w2, unsigned short* __restrict__ w2q) {
    __shared__ float tile[64][65];
    const int k0 = (blockIdx.x >> 4) * 64;
    const int u0 = (blockIdx.x & 15) * 64;
    const int t = threadIdx.x;  // 256
    {
        const int kr = t >> 2, uc = (t & 3) * 16;
        const float* src = w2 + (size_t)(k0 + kr) * UU + u0 + uc;
#pragma unroll
        for (int j = 0; j < 4; ++j) {
            f32x4 v = *reinterpret_cast<const f32x4*>(src + j * 4);
            tile[kr][uc + j * 4 + 0] = v[0]; tile[kr][uc + j * 4 + 1] = v[1];
            tile[kr][uc + j * 4 + 2] = v[2]; tile[kr][uc + j * 4 + 3] = v[3];
        }
    }
    __syncthreads();
    const int c = t >> 5;
    const int uqL = c >> 1, ksL = c & 1;
    const int uq = (u0 >> 4) + uqL, ks = (k0 >> 5) + ksL;
#pragma unroll
    for (int li = 0; li < 2; ++li) {
        const int l = (t & 31) * 2 + li;
        const int colL = uqL * 16 + (l & 15);
        const int kL = ksL * 32 + (l >> 4) * 8;
        bf16x8 pk;
#pragma unroll
        for (int e = 0; e < 8; ++e) pk[e] = (short)f2bf(tile[kL + e][colL]);
        *reinterpret_cast<bf16x8*>(&w2q[(size_t)(((uq * 32 + ks) * 64 + l)) * 8]) = pk;
    }
}

// ---------------- K2: fused GEMM + tanh + wv-reduce -> score[b,s] ----------------
// R20 structure with K-SPLIT LDS: Apk holds only 16 ks (64 KB) written modulo-4
// slice regions -> 68 KB LDS total -> TWO blocks/CU (8 waves/SIMD). One block's
// stage/barriers overlap the other's MFMA (the missing cross-block overlap).
// Slice being overwritten is >=3 barriers stale -> race-free.
__global__ __launch_bounds__(1024, 4)
void score_kernel(const float* __restrict__ values, const unsigned short* __restrict__ w2q,
                  const float* __restrict__ qp2, const float* __restrict__ wv,
                  const float* __restrict__ bv, float* __restrict__ score) {
    __shared__ __align__(16) unsigned short Apk[16 * 4 * 512];  // 64 KB, [ks&15][mf][512]
    __shared__ float ssum[16][MBLK];                             // 4 KB

    const int blk = blockIdx.x;        // 1024
    const int b = blk >> 5;
    const int s0 = (blk & 31) * MBLK;
    const int tid = threadIdx.x;
    const int lane = tid & 63;
    const int wid = tid >> 6;          // 0..15
    const int arow = lane & 15;
    const int uq0 = wid * 4;           // wave's 4 uq-blocks = 64 U cols

    // staging role: thread (row=tid>>4, g=tid&15); slice s covers cols s*128..+128;
    // within slice: ks_local = g>>2; q=g&3; frag-lane l=(row&15)+16*q, swz l^q; mf=row>>4
    const int row = tid >> 4;
    const int g = tid & 15;
    const int q = g & 3;
    const int lsw = ((row & 15) + 16 * q) ^ q;
    const float* src = values + ((size_t)b * SS + s0 + row) * DD + g * 8;
    unsigned short* sdst = Apk + (size_t)(g >> 2) * 2048 + (size_t)(row >> 4) * 512 + lsw * 8;

#define STAGE_W(preg, x, y)                                                \
    {                                                                      \
        u32 q0 = cvtpk((x)[0], (x)[1]), q1 = cvtpk((x)[2], (x)[3]);        \
        u32 q2 = cvtpk((y)[0], (y)[1]), q3 = cvtpk((y)[2], (y)[3]);        \
        i32x4 w_ = {(int)q0, (int)q1, (int)q2, (int)q3};                   \
        *reinterpret_cast<i32x4*>(sdst + (size_t)(preg) * 8192) = w_;      \
    }

    const unsigned short* Ab = Apk + (size_t)(lane ^ ((lane >> 4) & 3)) * 8;
    const unsigned short* wqs =
        w2q + ((size_t)__builtin_amdgcn_readfirstlane(wid) << 16);
    const size_t lane8 = (size_t)lane * 8;

    f32x4 acc[4][4];
#pragma unroll
    for (int mf = 0; mf < 4; ++mf)
#pragma unroll
        for (int nf = 0; nf < 4; ++nf) { f32x4 z = {0.f, 0.f, 0.f, 0.f}; acc[mf][nf] = z; }

    // prologue: stage slice 0 into region 0
    {
        f32x4 x0 = ntload4(src), y0 = ntload4(src + 4);
        STAGE_W(0, x0, y0);
    }
    __syncthreads();

#pragma unroll 1
    for (int s = 0; s < 8; ++s) {
        // issue loads for slice s+1 (in flight across this phase's compute)
        f32x4 L0, L1;
        if (s < 7) {
            const float* s1 = src + (s + 1) * 128;
            L0 = ntload4(s1);
            L1 = ntload4(s1 + 4);
        }
        // compute 4 ks of slice s (zero-barrier within phase)
#pragma unroll
        for (int kk = 0; kk < 4; ++kk) {
            const int ks = s * 4 + kk;       // 0..31 (B index)
            const int ksl = ks & 15;         // LDS region index
            bf16x8 aF[4];
#pragma unroll
            for (int mf = 0; mf < 4; ++mf)
                aF[mf] = *reinterpret_cast<const bf16x8*>(Ab + ((size_t)(ksl * 4 + mf) << 9));
            bf16x8 bF[4];
#pragma unroll
            for (int nf = 0; nf < 4; ++nf)
                bF[nf] = *reinterpret_cast<const bf16x8*>(
                    wqs + (((size_t)(nf * 32 + ks)) << 9) + lane8);
#pragma unroll
            for (int mf = 0; mf < 4; ++mf)
#pragma unroll
                for (int nf = 0; nf < 4; ++nf)
                    acc[mf][nf] = __builtin_amdgcn_mfma_f32_16x16x32_bf16(
                        aF[mf], bF[nf], acc[mf][nf], 0, 0, 0);
        }
        // write slice s+1 into region (s+1)&3, then make it visible
        if (s < 7) {
            STAGE_W((s + 1) & 3, L0, L1);
            __syncthreads();
        }
    }
#undef STAGE_W

    // epilogue: tanh + wv weighting (16x16 C/D: col=lane&15 (=u), row=(lane>>4)*4+i)
    float rowsum[16];
#pragma unroll
    for (int i = 0; i < 16; ++i) rowsum[i] = 0.f;
#pragma unroll
    for (int nf = 0; nf < 4; ++nf) {
        const int u = (uq0 + nf) * 16 + arow;
        const float qv = qp2[b * UU + u];
        const float wvv = wv[u];
#pragma unroll
        for (int mf = 0; mf < 4; ++mf)
#pragma unroll
            for (int i = 0; i < 4; ++i) {
                float h = acc[mf][nf][i] + qv;
                float e = __expf(2.f * h);
                float th = 1.f - 2.f / (e + 1.f);
                rowsum[mf * 4 + i] = fmaf(th, wvv, rowsum[mf * 4 + i]);
            }
    }
#pragma unroll
    for (int i = 0; i < 16; ++i) {
        float v = rowsum[i];
        v += __shfl_xor(v, 1);
        v += __shfl_xor(v, 2);
        v += __shfl_xor(v, 4);
        v += __shfl_xor(v, 8);
        rowsum[i] = v;
    }
    if ((lane & 15) == 0) {
        const int rg = lane >> 4;
#pragma unroll
        for (int mf = 0; mf < 4; ++mf)
#pragma unroll
            for (int i = 0; i < 4; ++i)
                ssum[wid][mf * 16 + rg * 4 + i] = rowsum[mf * 4 + i];
    }
    __syncthreads();
    if (tid < MBLK) {
        float sc = bv[0];
#pragma unroll
        for (int w = 0; w < 16; ++w) sc += ssum[w][tid];
        score[b * SS + s0 + tid] = sc;
    }
}

// ---------------- K3a: softmax over S per batch ----------------
__global__ void softmax_kernel(const float* __restrict__ score, float* __restrict__ weights) {
    __shared__ float red[8];
    const int b = blockIdx.x;
    const int t = threadIdx.x;  // 256
    float local[8];
    float mx = -1e30f;
#pragma unroll
    for (int i = 0; i < 8; ++i) {
        local[i] = score[b * SS + i * 256 + t];
        mx = fmaxf(mx, local[i]);
    }
    for (int off = 1; off < 64; off <<= 1) mx = fmaxf(mx, __shfl_xor(mx, off));
    if ((t & 63) == 0) red[t >> 6] = mx;
    __syncthreads();
    const float m = fmaxf(fmaxf(red[0], red[1]), fmaxf(red[2], red[3]));
    float sum = 0.f;
#pragma unroll
    for (int i = 0; i < 8; ++i) {
        local[i] = __expf(local[i] - m);
        sum += local[i];
    }
    for (int off = 1; off < 64; off <<= 1) sum += __shfl_xor(sum, off);
    if ((t & 63) == 0) red[4 + (t >> 6)] = sum;
    __syncthreads();
    const float inv = 1.f / (red[4] + red[5] + red[6] + red[7]);
#pragma unroll
    for (int i = 0; i < 8; ++i) weights[b * SS + i * 256 + t] = local[i] * inv;
}

// ---------------- K3b: context[b,d] = sum_s w[b,s] * values[b,s,d] ----------------
__global__ void context_kernel(const float* __restrict__ values, const float* __restrict__ weights,
                               float* __restrict__ ctx) {
    __shared__ float ws[SS];          // 8 KB
    __shared__ f32x4 red[16][16];     // 4 KB
    const int b = blockIdx.x;   // 32
    const int dc = blockIdx.y;  // 16
    const int t = threadIdx.x;  // 256
    for (int i = t; i < SS; i += 256) ws[i] = weights[b * SS + i];
    __syncthreads();
    const int dt = t & 15;      // 16 d-threads (64 cols)
    const int ph = t >> 4;      // 16 s-phases
    const int d = dc * 64 + dt * 4;
    const float* vb = values + (size_t)b * SS * DD + d;
    f32x4 acc = {0.f, 0.f, 0.f, 0.f};
#pragma unroll 8
    for (int s = ph; s < SS; s += 16) {
        const float w = ws[s];
        f32x4 v = ntload4(vb + (size_t)s * DD);
        acc[0] = fmaf(w, v[0], acc[0]);
        acc[1] = fmaf(w, v[1], acc[1]);
        acc[2] = fmaf(w, v[2], acc[2]);
        acc[3] = fmaf(w, v[3], acc[3]);
    }
    red[ph][dt] = acc;
    __syncthreads();
    if (t < 16) {
        f32x4 r = red[0][t];
#pragma unroll
        for (int w = 1; w < 16; ++w) {
            f32x4 x = red[w][t];
#pragma unroll
            for (int i = 0; i < 4; ++i) r[i] += x[i];
        }
        *reinterpret_cast<f32x4*>(ctx + (size_t)b * DD + dc * 64 + t * 4) = r;
    }
}

extern "C" void kernel_launch(void* const* d_in, const int* in_sizes, int n_in,
                              void* d_out, int out_size, void* d_ws, size_t ws_size,
                              hipStream_t stream) {
    const float* query  = (const float*)d_in[0];
    const float* values = (const float*)d_in[1];
    const float* w1     = (const float*)d_in[2];
    const float* b1     = (const float*)d_in[3];
    const float* w2     = (const float*)d_in[4];
    const float* b2     = (const float*)d_in[5];
    const float* wv     = (const float*)d_in[6];
    const float* bv     = (const float*)d_in[7];

    float* ctx     = (float*)d_out;                    // [B, D]
    float* weights = (float*)d_out + (size_t)BB * DD;  // [B, S, 1]

    float* qp2           = (float*)d_ws;                                  // 128 KB
    unsigned short* w2q  = (unsigned short*)((char*)d_ws + 131072);       // 2 MB
    float* score         = (float*)((char*)d_ws + 131072 + 2097152);      // 256 KB

    zero_kernel<<<dim3(BB * UU / 256), 256, 0, stream>>>(qp2);
    qproj_kernel<<<dim3(4, 8, 8), 256, 0, stream>>>(query, w1, b1, b2, qp2);
    w2q_kernel<<<dim3(256), 256, 0, stream>>>(w2, w2q);
    score_kernel<<<dim3(BB * SS / MBLK), 1024, 0, stream>>>(values, w2q, qp2, wv, bv, score);
    softmax_kernel<<<dim3(BB), 256, 0, stream>>>(score, weights);
    context_kernel<<<dim3(BB, 16), 256, 0, stream>>>(values, weights, ctx);
}

// Round 23
// 231.948 us; speedup vs baseline: 1.3339x; 1.3339x over previous
//
#include <hip/hip_runtime.h>
#include <hip/hip_bf16.h>

#define BB 32
#define SS 2048
#define DD 1024
#define UU 1024
#define MBLK 64

typedef short bf16x8 __attribute__((ext_vector_type(8)));
typedef float f32x4 __attribute__((ext_vector_type(4)));
typedef int i32x4 __attribute__((ext_vector_type(4)));
typedef unsigned short u16x4 __attribute__((ext_vector_type(4)));
typedef unsigned int u32;
typedef unsigned short u16;

__device__ __forceinline__ unsigned short f2bf(float x) {
    union { float f; unsigned int u; } v; v.f = x;
    unsigned int r = v.u + 0x7fffu + ((v.u >> 16) & 1u);
    return (unsigned short)(r >> 16);
}

__device__ __forceinline__ f32x4 ntload4(const float* p) {
    return __builtin_nontemporal_load(reinterpret_cast<const f32x4*>(p));
}

__device__ __forceinline__ u32 cvtpk(float lo, float hi) {
    u32 r;
    asm("v_cvt_pk_bf16_f32 %0, %1, %2" : "=v"(r) : "v"(lo), "v"(hi));
    return r;
}

__device__ __forceinline__ float bf2f(u16 h) {
    union { unsigned int u; float f; } v; v.u = ((unsigned int)h) << 16;
    return v.f;
}

// ---------------- K0: zero qp2 (qproj accumulates atomically) ----------------
__global__ void zero_kernel(float* __restrict__ qp2) {
    qp2[blockIdx.x * 256 + threadIdx.x] = 0.f;
}

// ---------------- K1a: q_proj partials = query@w1 (+b1+b2 on ds==0) ----------
__global__ void qproj_kernel(const float* __restrict__ query, const float* __restrict__ w1,
                             const float* __restrict__ b1, const float* __restrict__ b2,
                             float* __restrict__ qp2) {
    __shared__ float qs[4][128];
    const int uc = blockIdx.x;   // 4
    const int bg = blockIdx.y;   // 8
    const int ds = blockIdx.z;   // 8
    const int t = threadIdx.x;   // 256
    if (t < 128) {
#pragma unroll
        for (int bi = 0; bi < 4; ++bi)
            qs[bi][t] = query[(bg * 4 + bi) * DD + ds * 128 + t];
    }
    __syncthreads();
    const int u = uc * 256 + t;
    float a0 = 0.f, a1 = 0.f, a2 = 0.f, a3 = 0.f;
    const float* wp = w1 + (size_t)(ds * 128) * UU + u;
#pragma unroll 4
    for (int d = 0; d < 128; ++d) {
        const float w = wp[(size_t)d * UU];
        a0 = fmaf(qs[0][d], w, a0);
        a1 = fmaf(qs[1][d], w, a1);
        a2 = fmaf(qs[2][d], w, a2);
        a3 = fmaf(qs[3][d], w, a3);
    }
    const float bb = (ds == 0) ? (b1[u] + b2[u]) : 0.f;
    atomicAdd(&qp2[(bg * 4 + 0) * UU + u], a0 + bb);
    atomicAdd(&qp2[(bg * 4 + 1) * UU + u], a1 + bb);
    atomicAdd(&qp2[(bg * 4 + 2) * UU + u], a2 + bb);
    atomicAdd(&qp2[(bg * 4 + 3) * UU + u], a3 + bb);
}

// ---------------- K1b: fragment-packed B for 16x16x32 (coalesced via LDS) -----
__global__ void w2q_kernel(const float* __restrict__ w2, unsigned short* __restrict__ w2q) {
    __shared__ float tile[64][65];
    const int k0 = (blockIdx.x >> 4) * 64;
    const int u0 = (blockIdx.x & 15) * 64;
    const int t = threadIdx.x;  // 256
    {
        const int kr = t >> 2, uc = (t & 3) * 16;
        const float* src = w2 + (size_t)(k0 + kr) * UU + u0 + uc;
#pragma unroll
        for (int j = 0; j < 4; ++j) {
            f32x4 v = *reinterpret_cast<const f32x4*>(src + j * 4);
            tile[kr][uc + j * 4 + 0] = v[0]; tile[kr][uc + j * 4 + 1] = v[1];
            tile[kr][uc + j * 4 + 2] = v[2]; tile[kr][uc + j * 4 + 3] = v[3];
        }
    }
    __syncthreads();
    const int c = t >> 5;
    const int uqL = c >> 1, ksL = c & 1;
    const int uq = (u0 >> 4) + uqL, ks = (k0 >> 5) + ksL;
#pragma unroll
    for (int li = 0; li < 2; ++li) {
        const int l = (t & 31) * 2 + li;
        const int colL = uqL * 16 + (l & 15);
        const int kL = ksL * 32 + (l >> 4) * 8;
        bf16x8 pk;
#pragma unroll
        for (int e = 0; e < 8; ++e) pk[e] = (short)f2bf(tile[kL + e][colL]);
        *reinterpret_cast<bf16x8*>(&w2q[(size_t)(((uq * 32 + ks) * 64 + l)) * 8]) = pk;
    }
}

// ---------------- K2: fused GEMM + tanh + wv-reduce -> score[b,s] ----------------
// R20-exact structure (best known: 186 us) + OPTIONAL bf16 writeback: the staged
// bf16 packets (already in regs) are nt-stored to vbf so context reads 128 MB not 256.
__global__ __launch_bounds__(1024, 4)
void score_kernel(const float* __restrict__ values, const unsigned short* __restrict__ w2q,
                  const float* __restrict__ qp2, const float* __restrict__ wv,
                  const float* __restrict__ bv, float* __restrict__ score,
                  unsigned short* __restrict__ vbf) {
    __shared__ __align__(16) unsigned short Apk[MBLK * DD];  // 128 KB, [ks][mf][512]
    __shared__ float ssum[16][MBLK];                          // 4 KB

    const int blk = blockIdx.x;        // 1024
    const int b = blk >> 5;
    const int s0 = (blk & 31) * MBLK;
    const int tid = threadIdx.x;
    const int lane = tid & 63;
    const int wid = tid >> 6;          // 0..15
    const int arow = lane & 15;
    const int uq0 = wid * 4;           // wave's 4 uq-blocks = 64 U cols

    // staging role: thread (row=tid>>4, g=tid&15); per phase p covers col g*8+p*128
    const int row = tid >> 4;
    const int g = tid & 15;
    const int q = g & 3;
    const int lsw = ((row & 15) + 16 * q) ^ q;
    const size_t elem0 = ((size_t)b * SS + s0 + row) * DD + g * 8;
    const float* src = values + elem0;
    unsigned short* vdst = vbf ? (vbf + elem0) : nullptr;
    unsigned short* sdst = Apk + (size_t)(g >> 2) * 2048 + (size_t)(row >> 4) * 512 + lsw * 8;

#define STAGE_W(p, x, y)                                                       \
    {                                                                          \
        u32 q0 = cvtpk((x)[0], (x)[1]), q1 = cvtpk((x)[2], (x)[3]);            \
        u32 q2 = cvtpk((y)[0], (y)[1]), q3 = cvtpk((y)[2], (y)[3]);            \
        i32x4 w_ = {(int)q0, (int)q1, (int)q2, (int)q3};                       \
        *reinterpret_cast<i32x4*>(sdst + (size_t)(p) * 8192) = w_;             \
        if (vdst)                                                              \
            __builtin_nontemporal_store(                                       \
                w_, reinterpret_cast<i32x4*>(vdst + (size_t)(p) * 128));       \
    }

    const unsigned short* Ab = Apk + (size_t)(lane ^ ((lane >> 4) & 3)) * 8;
    const unsigned short* wqs =
        w2q + ((size_t)__builtin_amdgcn_readfirstlane(wid) << 16);
    const size_t lane8 = (size_t)lane * 8;

    f32x4 acc[4][4];
#pragma unroll
    for (int mf = 0; mf < 4; ++mf)
#pragma unroll
        for (int nf = 0; nf < 4; ++nf) { f32x4 z = {0.f, 0.f, 0.f, 0.f}; acc[mf][nf] = z; }

    // prologue: stage slice 0
    {
        f32x4 x0 = ntload4(src), y0 = ntload4(src + 4);
        STAGE_W(0, x0, y0);
    }
    __syncthreads();

#pragma unroll 1
    for (int p = 0; p < 8; ++p) {
        f32x4 L0, L1;
        if (p < 7) {
            const float* s1 = src + (p + 1) * 128;
            L0 = ntload4(s1);
            L1 = ntload4(s1 + 4);
        }
#pragma unroll
        for (int kk = 0; kk < 4; ++kk) {
            const int ks = p * 4 + kk;
            bf16x8 aF[4];
#pragma unroll
            for (int mf = 0; mf < 4; ++mf)
                aF[mf] = *reinterpret_cast<const bf16x8*>(Ab + ((size_t)(ks * 4 + mf) << 9));
            bf16x8 bF[4];
#pragma unroll
            for (int nf = 0; nf < 4; ++nf)
                bF[nf] = *reinterpret_cast<const bf16x8*>(
                    wqs + (((size_t)(nf * 32 + ks)) << 9) + lane8);
#pragma unroll
            for (int mf = 0; mf < 4; ++mf)
#pragma unroll
                for (int nf = 0; nf < 4; ++nf)
                    acc[mf][nf] = __builtin_amdgcn_mfma_f32_16x16x32_bf16(
                        aF[mf], bF[nf], acc[mf][nf], 0, 0, 0);
        }
        if (p < 7) {
            STAGE_W(p + 1, L0, L1);
            __syncthreads();
        }
    }
#undef STAGE_W

    // epilogue: tanh + wv weighting (16x16 C/D: col=lane&15 (=u), row=(lane>>4)*4+i)
    float rowsum[16];
#pragma unroll
    for (int i = 0; i < 16; ++i) rowsum[i] = 0.f;
#pragma unroll
    for (int nf = 0; nf < 4; ++nf) {
        const int u = (uq0 + nf) * 16 + arow;
        const float qv = qp2[b * UU + u];
        const float wvv = wv[u];
#pragma unroll
        for (int mf = 0; mf < 4; ++mf)
#pragma unroll
            for (int i = 0; i < 4; ++i) {
                float h = acc[mf][nf][i] + qv;
                float e = __expf(2.f * h);
                float th = 1.f - 2.f / (e + 1.f);
                rowsum[mf * 4 + i] = fmaf(th, wvv, rowsum[mf * 4 + i]);
            }
    }
#pragma unroll
    for (int i = 0; i < 16; ++i) {
        float v = rowsum[i];
        v += __shfl_xor(v, 1);
        v += __shfl_xor(v, 2);
        v += __shfl_xor(v, 4);
        v += __shfl_xor(v, 8);
        rowsum[i] = v;
    }
    if ((lane & 15) == 0) {
        const int rg = lane >> 4;
#pragma unroll
        for (int mf = 0; mf < 4; ++mf)
#pragma unroll
            for (int i = 0; i < 4; ++i)
                ssum[wid][mf * 16 + rg * 4 + i] = rowsum[mf * 4 + i];
    }
    __syncthreads();
    if (tid < MBLK) {
        float sc = bv[0];
#pragma unroll
        for (int w = 0; w < 16; ++w) sc += ssum[w][tid];
        score[b * SS + s0 + tid] = sc;
    }
}

// ---------------- K3a: softmax over S per batch ----------------
__global__ void softmax_kernel(const float* __restrict__ score, float* __restrict__ weights) {
    __shared__ float red[8];
    const int b = blockIdx.x;
    const int t = threadIdx.x;  // 256
    float local[8];
    float mx = -1e30f;
#pragma unroll
    for (int i = 0; i < 8; ++i) {
        local[i] = score[b * SS + i * 256 + t];
        mx = fmaxf(mx, local[i]);
    }
    for (int off = 1; off < 64; off <<= 1) mx = fmaxf(mx, __shfl_xor(mx, off));
    if ((t & 63) == 0) red[t >> 6] = mx;
    __syncthreads();
    const float m = fmaxf(fmaxf(red[0], red[1]), fmaxf(red[2], red[3]));
    float sum = 0.f;
#pragma unroll
    for (int i = 0; i < 8; ++i) {
        local[i] = __expf(local[i] - m);
        sum += local[i];
    }
    for (int off = 1; off < 64; off <<= 1) sum += __shfl_xor(sum, off);
    if ((t & 63) == 0) red[4 + (t >> 6)] = sum;
    __syncthreads();
    const float inv = 1.f / (red[4] + red[5] + red[6] + red[7]);
#pragma unroll
    for (int i = 0; i < 8; ++i) weights[b * SS + i * 256 + t] = local[i] * inv;
}

// ---------------- K3b-f32: context from f32 values (fallback) ----------------
__global__ void context_kernel(const float* __restrict__ values, const float* __restrict__ weights,
                               float* __restrict__ ctx) {
    __shared__ float ws[SS];          // 8 KB
    __shared__ f32x4 red[16][16];     // 4 KB
    const int b = blockIdx.x;   // 32
    const int dc = blockIdx.y;  // 16
    const int t = threadIdx.x;  // 256
    for (int i = t; i < SS; i += 256) ws[i] = weights[b * SS + i];
    __syncthreads();
    const int dt = t & 15;
    const int ph = t >> 4;
    const int d = dc * 64 + dt * 4;
    const float* vb = values + (size_t)b * SS * DD + d;
    f32x4 acc = {0.f, 0.f, 0.f, 0.f};
#pragma unroll 8
    for (int s = ph; s < SS; s += 16) {
        const float w = ws[s];
        f32x4 v = ntload4(vb + (size_t)s * DD);
        acc[0] = fmaf(w, v[0], acc[0]);
        acc[1] = fmaf(w, v[1], acc[1]);
        acc[2] = fmaf(w, v[2], acc[2]);
        acc[3] = fmaf(w, v[3], acc[3]);
    }
    red[ph][dt] = acc;
    __syncthreads();
    if (t < 16) {
        f32x4 r = red[0][t];
#pragma unroll
        for (int w = 1; w < 16; ++w) {
            f32x4 x = red[w][t];
#pragma unroll
            for (int i = 0; i < 4; ++i) r[i] += x[i];
        }
        *reinterpret_cast<f32x4*>(ctx + (size_t)b * DD + dc * 64 + t * 4) = r;
    }
}

// ---------------- K3b-bf16: context from bf16 values copy (128 MB read) --------
__global__ void context_bf16_kernel(const unsigned short* __restrict__ vbf,
                                    const float* __restrict__ weights,
                                    float* __restrict__ ctx) {
    __shared__ float ws[SS];          // 8 KB
    __shared__ f32x4 red[16][16];     // 4 KB
    const int b = blockIdx.x;   // 32
    const int dc = blockIdx.y;  // 16
    const int t = threadIdx.x;  // 256
    for (int i = t; i < SS; i += 256) ws[i] = weights[b * SS + i];
    __syncthreads();
    const int dt = t & 15;
    const int ph = t >> 4;
    const int d = dc * 64 + dt * 4;
    const unsigned short* vb = vbf + (size_t)b * SS * DD + d;
    f32x4 acc = {0.f, 0.f, 0.f, 0.f};
#pragma unroll 8
    for (int s = ph; s < SS; s += 16) {
        const float w = ws[s];
        u16x4 v = __builtin_nontemporal_load(
            reinterpret_cast<const u16x4*>(vb + (size_t)s * DD));
        acc[0] = fmaf(w, bf2f(v[0]), acc[0]);
        acc[1] = fmaf(w, bf2f(v[1]), acc[1]);
        acc[2] = fmaf(w, bf2f(v[2]), acc[2]);
        acc[3] = fmaf(w, bf2f(v[3]), acc[3]);
    }
    red[ph][dt] = acc;
    __syncthreads();
    if (t < 16) {
        f32x4 r = red[0][t];
#pragma unroll
        for (int w = 1; w < 16; ++w) {
            f32x4 x = red[w][t];
#pragma unroll
            for (int i = 0; i < 4; ++i) r[i] += x[i];
        }
        *reinterpret_cast<f32x4*>(ctx + (size_t)b * DD + dc * 64 + t * 4) = r;
    }
}

extern "C" void kernel_launch(void* const* d_in, const int* in_sizes, int n_in,
                              void* d_out, int out_size, void* d_ws, size_t ws_size,
                              hipStream_t stream) {
    const float* query  = (const float*)d_in[0];
    const float* values = (const float*)d_in[1];
    const float* w1     = (const float*)d_in[2];
    const float* b1     = (const float*)d_in[3];
    const float* w2     = (const float*)d_in[4];
    const float* b2     = (const float*)d_in[5];
    const float* wv     = (const float*)d_in[6];
    const float* bv     = (const float*)d_in[7];

    float* ctx     = (float*)d_out;                    // [B, D]
    float* weights = (float*)d_out + (size_t)BB * DD;  // [B, S, 1]

    float* qp2           = (float*)d_ws;                                  // 128 KB
    unsigned short* w2q  = (unsigned short*)((char*)d_ws + 131072);       // 2 MB
    float* score         = (float*)((char*)d_ws + 131072 + 2097152);      // 256 KB

    const size_t vbf_off = 131072 + 2097152 + 262144;
    const size_t vbf_bytes = (size_t)BB * SS * DD * 2;  // 128 MB
    unsigned short* vbf = (ws_size >= vbf_off + vbf_bytes)
                              ? (unsigned short*)((char*)d_ws + vbf_off)
                              : nullptr;

    zero_kernel<<<dim3(BB * UU / 256), 256, 0, stream>>>(qp2);
    qproj_kernel<<<dim3(4, 8, 8), 256, 0, stream>>>(query, w1, b1, b2, qp2);
    w2q_kernel<<<dim3(256), 256, 0, stream>>>(w2, w2q);
    score_kernel<<<dim3(BB * SS / MBLK), 1024, 0, stream>>>(values, w2q, qp2, wv, bv, score, vbf);
    softmax_kernel<<<dim3(BB), 256, 0, stream>>>(score, weights);
    if (vbf)
        context_bf16_kernel<<<dim3(BB, 16), 256, 0, stream>>>(vbf, weights, ctx);
    else
        context_kernel<<<dim3(BB, 16), 256, 0, stream>>>(values, weights, ctx);
}